// Round 10
// baseline (318.978 us; speedup 1.0000x reference)
//
#include <hip/hip_runtime.h>

// ClassicPINN forward, round 7 kernel (4th submit — three consecutive benches
// lost to GPU acquisition timeouts; this exact source has never run).
// Round-6 post-mortem: f32x2 point-packing cut VALU busy 164->126us but dur
// only 191->183us — freed cycles became stall. Occupancy 30% (~168 VGPR,
// 2.5 waves/SIMD) can't hide ~1280 ds_read->FMA dependent chains.
// Fix: pack NEURON pairs (j,j+1) into f32x2 instead of point pairs, W stored
// TRANSPOSED in LDS (k-major) so weight pairs are contiguous (ds_read_b128 =
// 4 neurons, zero broadcast movs); activation broadcast {h_k,h_k} hoisted to
// once per k (219/thread). Same pk_fma count/point, half the register state
// (h[32]+acc[16 pairs] ~ 100 VGPR) -> 5 waves/SIMD latency hiding.
// Summation order per output j unchanged (k-ascending) -> bit-identical.

#define NPTS 1048576

typedef float f32x2 __attribute__((ext_vector_type(2)));

struct PinnParams {
    const float* W[15];
    const float* B[15];
};

// Layer geometry (floats), compile-time.
__constant__ constexpr int kIN[15]   = {3, 8, 8, 8, 8, 8, 8, 8, 16, 16, 16, 32, 32, 32, 16};
__constant__ constexpr int kOUT[15]  = {8, 8, 8, 8, 8, 8, 8, 16, 16, 16, 32, 32, 32, 16, 3};
__constant__ constexpr int kWSZ[15]  = {24, 64, 64, 64, 64, 64, 64, 128, 256, 256, 512, 1024, 1024, 512, 48};
__constant__ constexpr int kWOFF[15] = {0, 24, 88, 152, 216, 280, 344, 408, 536, 792, 1048, 1560, 2584, 3608, 4120};
__constant__ constexpr int kBOFF[15] = {0, 8, 16, 24, 32, 40, 48, 56, 72, 88, 104, 136, 168, 200, 216};
#define WTOT 4168
#define BTOT 219

__device__ __forceinline__ float fast_tanh(float x) {
    // tanh(x) = 1 - 2/(exp(2x)+1); exp(2x)=exp2(x*2*log2e). Clamp +-9.5
    // (v_med3_f32) saturates to 1.0f exactly like tanhf. Bit-identical to
    // rounds 1-6 (absmax 9.77e-4, passed).
    x = __builtin_amdgcn_fmed3f(x, -9.5f, 9.5f);
    float e = __builtin_amdgcn_exp2f(x * 2.8853900817779268f);
    return 1.0f - 2.0f * __builtin_amdgcn_rcpf(e + 1.0f);
}

// Generic layer, neuron-pair packed, W^T (k-major) in LDS. OUT % 4 == 0.
// h: float[IN] in registers; o: float[OUT] in registers (static idx only).
template <int L, bool TANH>
__device__ __forceinline__ void layerT(const float* __restrict__ ldswT,
                                       const float* __restrict__ ldsb,
                                       const float* h, float* o) {
    constexpr int IN = kIN[L], OUT = kOUT[L], WO = kWOFF[L], BO = kBOFF[L];
    static_assert(OUT % 4 == 0, "generic path needs OUT%4==0");
    f32x2 acc[OUT / 2];
#pragma unroll
    for (int j2 = 0; j2 < OUT / 2; ++j2)  // bias pairs: uniform ds_read_b64
        acc[j2] = *reinterpret_cast<const f32x2*>(ldsb + BO + 2 * j2);
#pragma unroll
    for (int k = 0; k < IN; ++k) {
        const float hk = h[k];
        const f32x2 hb = {hk, hk};  // one broadcast per k, reused OUT/2 times
        const float* wrow = ldswT + WO + k * OUT;  // W^T row: j contiguous
#pragma unroll
        for (int j4 = 0; j4 < OUT / 4; ++j4) {
            // uniform ds_read_b128: weights for 4 neurons at this k
            const float4 w = *reinterpret_cast<const float4*>(wrow + 4 * j4);
            acc[2 * j4 + 0] = __builtin_elementwise_fma(f32x2{w.x, w.y}, hb, acc[2 * j4 + 0]);
            acc[2 * j4 + 1] = __builtin_elementwise_fma(f32x2{w.z, w.w}, hb, acc[2 * j4 + 1]);
        }
    }
#pragma unroll
    for (int j2 = 0; j2 < OUT / 2; ++j2) {
        o[2 * j2 + 0] = TANH ? fast_tanh(acc[j2].x) : acc[j2].x;
        o[2 * j2 + 1] = TANH ? fast_tanh(acc[j2].y) : acc[j2].y;
    }
}

// Last layer: 16 -> 3, no tanh, scalar accumulators (OUT=3 not packable).
__device__ __forceinline__ void layer14(const float* __restrict__ ldswT,
                                        const float* __restrict__ ldsb,
                                        const float* h, float* o) {
    constexpr int WO = kWOFF[14], BO = kBOFF[14];
    float a0 = ldsb[BO + 0], a1 = ldsb[BO + 1], a2 = ldsb[BO + 2];
#pragma unroll
    for (int k = 0; k < 16; ++k) {
        const float* wrow = ldswT + WO + k * 3;
        a0 = fmaf(wrow[0], h[k], a0);
        a1 = fmaf(wrow[1], h[k], a1);
        a2 = fmaf(wrow[2], h[k], a2);
    }
    o[0] = a0; o[1] = a1; o[2] = a2;
}

__global__ __launch_bounds__(256, 4) void pinn_fwd(const float* __restrict__ coords,
                                                   PinnParams prm,
                                                   float* __restrict__ out) {
    __shared__ __align__(16) float ldswT[WTOT];  // transposed: [k][j] per layer
    __shared__ float ldsb[BTOT];

    // ---- stage W^T + biases to LDS (once per block) ----
    const int tid = threadIdx.x;
    for (int l = 0; l < 15; ++l) {
        const float* __restrict__ W = prm.W[l];
        const int IN = kIN[l], OUT = kOUT[l], WO = kWOFF[l], SZ = kWSZ[l];
        for (int idx = tid; idx < SZ; idx += 256) {
            const int j = idx / IN, k = idx - j * IN;  // W row-major [j][k]
            ldswT[WO + k * OUT + j] = W[idx];
        }
        if (tid < OUT) ldsb[kBOFF[l] + tid] = prm.B[l][tid];
    }
    __syncthreads();

    // ---- one point per thread ----
    const int t = blockIdx.x * 256 + tid;
    float a[32], c[32];  // ping-pong activations, static indices only
    a[0] = coords[3 * t + 0];
    a[1] = coords[3 * t + 1];
    a[2] = coords[3 * t + 2];

    layerT<0, true>(ldswT, ldsb, a, c);   // 3 -> 8
    layerT<1, true>(ldswT, ldsb, c, a);
    layerT<2, true>(ldswT, ldsb, a, c);
    layerT<3, true>(ldswT, ldsb, c, a);
    layerT<4, true>(ldswT, ldsb, a, c);
    layerT<5, true>(ldswT, ldsb, c, a);
    layerT<6, true>(ldswT, ldsb, a, c);
    layerT<7, true>(ldswT, ldsb, c, a);   // 8 -> 16
    layerT<8, true>(ldswT, ldsb, a, c);
    layerT<9, true>(ldswT, ldsb, c, a);
    layerT<10, true>(ldswT, ldsb, a, c);  // 16 -> 32
    layerT<11, true>(ldswT, ldsb, c, a);
    layerT<12, true>(ldswT, ldsb, a, c);
    layerT<13, true>(ldswT, ldsb, c, a);  // 32 -> 16
    layer14(ldswT, ldsb, a, c);           // 16 -> 3, no tanh

    // outputs concatenated (h[:,0], h[:,1], h[:,2]); out[t] coalesced
    out[t] = c[0];
    out[NPTS + t] = c[1];
    out[2 * NPTS + t] = c[2];
}

extern "C" void kernel_launch(void* const* d_in, const int* in_sizes, int n_in,
                              void* d_out, int out_size, void* d_ws, size_t ws_size,
                              hipStream_t stream) {
    const float* coords = (const float*)d_in[0];
    PinnParams prm;
    for (int l = 0; l < 15; ++l) {
        prm.W[l] = (const float*)d_in[1 + 2 * l];
        prm.B[l] = (const float*)d_in[2 + 2 * l];
    }
    pinn_fwd<<<NPTS / 256, 256, 0, stream>>>(coords, prm, (float*)d_out);
}

// Round 12
// 243.160 us; speedup vs baseline: 1.3118x; 1.3118x over previous
//
#include <hip/hip_runtime.h>

// ClassicPINN forward, round 11 kernel (2nd submit — round-11 bench lost to
// GPU acquisition timeout; this exact source has never run).
// Round-10 post-mortem: neuron-pair + W^T-in-LDS REGRESSED (183->228us):
// ds_read_b128 per point doubled (1042 vs 521; each read fed only 2 pk_fma)
// and the transpose staging writes were 32-way bank-conflicted (1.07e7
// SQ_LDS_BANK_CONFLICT). LDS-path weights cost a vector-memory op per reuse.
// Fix: NO LDS. Pack the k-dimension into f32x2 (matches row-major W), read
// weights directly from global via uniform compile-time-offset addresses ->
// compiler emits s_load (SMEM pipe, SGPR operands feed v_pk_fma directly;
// rounds 1/4 SGPR=112 prove it scalarizes). One horizontal add per neuron.
// P=1 point/thread: h2[16]+o2[16] ~ 76 VGPR -> ~6 waves/SIMD so trans-pipe
// (exp2/rcp) and SMEM latency hide across waves.

#define NPTS 1048576

typedef float f32x2 __attribute__((ext_vector_type(2)));

struct PinnParams {
    const float* W[15];
    const float* B[15];
};

__device__ __forceinline__ float fast_tanh(float x) {
    // tanh(x) = 1 - 2/(exp(2x)+1); exp(2x)=exp2(x*2*log2e). Clamp +-9.5
    // (v_med3_f32) saturates to 1.0f exactly like tanhf. Same as rounds 1-10.
    x = __builtin_amdgcn_fmed3f(x, -9.5f, 9.5f);
    float e = __builtin_amdgcn_exp2f(x * 2.8853900817779268f);
    return 1.0f - 2.0f * __builtin_amdgcn_rcpf(e + 1.0f);
}

// Generic layer, k-pair packed, weights from GLOBAL (uniform -> s_load).
// h2: f32x2[IN/2] activations; o2: f32x2[OUT/2] outputs (halves written with
// static indices). acc2.x accumulates bias+even-k, acc2.y odd-k terms.
template <int IN, int OUT, bool TANH>
__device__ __forceinline__ void layerK(const float* __restrict__ W,
                                       const float* __restrict__ B,
                                       const f32x2* h2, f32x2* o2) {
    static_assert(IN % 2 == 0 && OUT % 2 == 0, "");
#pragma unroll
    for (int j = 0; j < OUT; ++j) {
        f32x2 acc = {B[j], 0.0f};  // B[j]: uniform s_load
#pragma unroll
        for (int k2 = 0; k2 < IN / 2; ++k2) {
            // uniform address, row-major pair -> s_load_dwordx2 (SGPR pair)
            const f32x2 w = *reinterpret_cast<const f32x2*>(W + j * IN + 2 * k2);
            acc = __builtin_elementwise_fma(w, h2[k2], acc);
        }
        const float s = acc.x + acc.y;
        const float r = TANH ? fast_tanh(s) : s;
        if (j & 1) o2[j >> 1].y = r; else o2[j >> 1].x = r;
    }
}

// First layer: 3 -> 8, scalar (IN=3 not pair-able; 24 weights).
__device__ __forceinline__ void layer0(const float* __restrict__ W,
                                       const float* __restrict__ B,
                                       float h0, float h1, float h2v, f32x2* o2) {
#pragma unroll
    for (int j = 0; j < 8; ++j) {
        float s = fmaf(W[3 * j + 0], h0, B[j]);
        s = fmaf(W[3 * j + 1], h1, s);
        s = fmaf(W[3 * j + 2], h2v, s);
        const float r = fast_tanh(s);
        if (j & 1) o2[j >> 1].y = r; else o2[j >> 1].x = r;
    }
}

// Last layer: 16 -> 3, no tanh.
__device__ __forceinline__ void layer14(const float* __restrict__ W,
                                        const float* __restrict__ B,
                                        const f32x2* h2, float* o) {
#pragma unroll
    for (int j = 0; j < 3; ++j) {
        f32x2 acc = {B[j], 0.0f};
#pragma unroll
        for (int k2 = 0; k2 < 8; ++k2) {
            const f32x2 w = *reinterpret_cast<const f32x2*>(W + j * 16 + 2 * k2);
            acc = __builtin_elementwise_fma(w, h2[k2], acc);
        }
        o[j] = acc.x + acc.y;
    }
}

__global__ __launch_bounds__(256, 6) void pinn_fwd(const float* __restrict__ coords,
                                                   PinnParams prm,
                                                   float* __restrict__ out) {
    const int t = blockIdx.x * 256 + threadIdx.x;

    // activations as f32x2 pairs, ping-pong; static indices only
    f32x2 a2[16], c2[16];
    const float x = coords[3 * t + 0];
    const float y = coords[3 * t + 1];
    const float z = coords[3 * t + 2];

    layer0(prm.W[0], prm.B[0], x, y, z, a2);          // 3 -> 8
    layerK<8, 8, true>(prm.W[1], prm.B[1], a2, c2);
    layerK<8, 8, true>(prm.W[2], prm.B[2], c2, a2);
    layerK<8, 8, true>(prm.W[3], prm.B[3], a2, c2);
    layerK<8, 8, true>(prm.W[4], prm.B[4], c2, a2);
    layerK<8, 8, true>(prm.W[5], prm.B[5], a2, c2);
    layerK<8, 8, true>(prm.W[6], prm.B[6], c2, a2);
    layerK<8, 16, true>(prm.W[7], prm.B[7], a2, c2);  // 8 -> 16
    layerK<16, 16, true>(prm.W[8], prm.B[8], c2, a2);
    layerK<16, 16, true>(prm.W[9], prm.B[9], a2, c2);
    layerK<16, 32, true>(prm.W[10], prm.B[10], c2, a2); // 16 -> 32
    layerK<32, 32, true>(prm.W[11], prm.B[11], a2, c2);
    layerK<32, 32, true>(prm.W[12], prm.B[12], c2, a2);
    layerK<32, 16, true>(prm.W[13], prm.B[13], a2, c2); // 32 -> 16
    float o[3];
    layer14(prm.W[14], prm.B[14], c2, o);             // 16 -> 3, no tanh

    // outputs concatenated (h[:,0], h[:,1], h[:,2]); out[t] coalesced
    out[t] = o[0];
    out[NPTS + t] = o[1];
    out[2 * NPTS + t] = o[2];
}

extern "C" void kernel_launch(void* const* d_in, const int* in_sizes, int n_in,
                              void* d_out, int out_size, void* d_ws, size_t ws_size,
                              hipStream_t stream) {
    const float* coords = (const float*)d_in[0];
    PinnParams prm;
    for (int l = 0; l < 15; ++l) {
        prm.W[l] = (const float*)d_in[1 + 2 * l];
        prm.B[l] = (const float*)d_in[2 + 2 * l];
    }
    pinn_fwd<<<NPTS / 256, 256, 0, stream>>>(coords, prm, (float*)d_out);
}